// Round 2
// baseline (180.083 us; speedup 1.0000x reference)
//
#include <hip/hip_runtime.h>

typedef _Float16 half8 __attribute__((ext_vector_type(8)));
typedef float floatx4 __attribute__((ext_vector_type(4)));

constexpr int C = 32, H = 512, W = 512, HW = H * W;
constexpr int TBH = 4;             // output rows per block
constexpr int TBW = 32;            // output px per block (2 waves x 16 px x 2 ch-halves)
constexpr int RR  = TBH + 2;       // staged input rows (h0-1 .. h0+4)
constexpr int PX  = TBW + 8;       // 40 staged px per row (w0-4 .. w0+35)
constexpr int PXW = 20;            // words per pixel: 16 x-fp16 + 2 depth(e-,e+) + 2 pad
constexpr int ROWW = PX * PXW + 8; // 808 words; 808 % 32 == 8 spreads row base banks

__device__ __forceinline__ unsigned pack2h(float lo, float hi) {
    unsigned a = (unsigned)__builtin_bit_cast(unsigned short, (_Float16)lo);
    unsigned b = (unsigned)__builtin_bit_cast(unsigned short, (_Float16)hi);
    return a | (b << 16);
}

// ---- tiny kernel: weights -> per-lane fp16 A-fragment uint4s (18.4 KB, L2-hot)
__global__ __launch_bounds__(256) void pack_w(const float* __restrict__ weight,
                                              uint4* __restrict__ wp) {
    int j = blockIdx.x * 256 + threadIdx.x;
    if (j >= 1152) return;                       // 9 taps * 2 halves * 64 lanes
    int lane = j & 63, half = (j >> 6) & 1, tap = j >> 7;
    int o = half * 16 + (lane & 15), q = lane >> 4;
    uint4 v;
    v.x = pack2h(weight[(o * 32 + q * 8 + 0) * 9 + tap], weight[(o * 32 + q * 8 + 1) * 9 + tap]);
    v.y = pack2h(weight[(o * 32 + q * 8 + 2) * 9 + tap], weight[(o * 32 + q * 8 + 3) * 9 + tap]);
    v.z = pack2h(weight[(o * 32 + q * 8 + 4) * 9 + tap], weight[(o * 32 + q * 8 + 5) * 9 + tap]);
    v.w = pack2h(weight[(o * 32 + q * 8 + 6) * 9 + tap], weight[(o * 32 + q * 8 + 7) * 9 + tap]);
    wp[j] = v;
}

// ---- fused conv. LDS layout: [RR rows][PX px][20 words] where words 0..15 are
// 32ch fp16 (chunk q = words 4q..4q+3 = channels 8q..8q+7), words 16..17 are
// (exp(-8.3d), exp(+8.3d)). Pixel stride 20 words (gcd(20,32)=4) makes both
// ds_write_b128 and ds_read_b128 exactly 8 words/bank = minimum: conflict-free.
__global__ __launch_bounds__(256, 4) void depthconv_fused(
    const float* __restrict__ x, const float* __restrict__ depth,
    const uint4* __restrict__ wp, const float* __restrict__ bias,
    float* __restrict__ out)
{
    __shared__ __attribute__((aligned(16))) unsigned xsl[RR * ROWW];  // 19.4 KB

    const int bid  = blockIdx.x;                 // b(2) x hseg(128) x wseg(16)
    const int wseg = bid & 15, hseg = (bid >> 4) & 127, b = bid >> 11;
    const int h0 = hseg * TBH, w0 = wseg * TBW;
    const int tid = threadIdx.x;

    const int lane = tid & 63, wid = tid >> 6;
    const int nn = lane & 15, q = lane >> 4;
    const int chh = wid >> 1;                    // output-channel half (0: 0-15, 1: 16-31)
    const int pcl = (wid & 1) * 16 + nn;         // tile-local output px 0..31

    // A-frags + bias from global first: latency overlaps stage-1 loads
    half8 af[9];
    #pragma unroll
    for (int tap = 0; tap < 9; ++tap)
        af[tap] = __builtin_bit_cast(half8, wp[(tap * 2 + chh) * 64 + lane]);

    floatx4 acc[TBH];                            // C/D: col=pixel nn, row(o)=4q+i
    #pragma unroll
    for (int i = 0; i < 4; ++i) {
        float bv = bias[chh * 16 + q * 4 + i];
        #pragma unroll
        for (int o = 0; o < TBH; ++o) acc[o][i] = bv;
    }

    // ---- stage 1a: x NCHW fp32 -> LDS fp16. unit = (chunk qc, row r, px):
    // 8 coalesced scalar loads (channels 8qc..8qc+7 at same px) -> 1 ds_write_b128.
    for (int u = tid; u < 4 * RR * PX; u += 256) {   // 960 units
        int px = u % PX, t = u / PX;
        int r = t % RR, qc = t / RR;
        int h = h0 - 1 + r, ww = w0 - 4 + px;
        bool valid = ((unsigned)h < (unsigned)H) && ((unsigned)ww < (unsigned)W);
        const float* xb = x + ((size_t)(b * C + 8 * qc)) * HW + (size_t)h * W + ww;
        float v[8];
        #pragma unroll
        for (int k = 0; k < 8; ++k)
            v[k] = valid ? xb[(size_t)k * HW] : 0.f;
        uint4 o4;
        o4.x = pack2h(v[0], v[1]); o4.y = pack2h(v[2], v[3]);
        o4.z = pack2h(v[4], v[5]); o4.w = pack2h(v[6], v[7]);
        *(uint4*)&xsl[r * ROWW + px * PXW + 4 * qc] = o4;
    }

    // ---- stage 1b: depth -> (e^-8.3d, e^+8.3d) at words 16..17 of each pixel
    for (int u = tid; u < RR * PX; u += 256) {       // 240 units
        int px = u % PX, r = u / PX;
        int h = h0 - 1 + r, ww = w0 - 4 + px;
        bool valid = ((unsigned)h < (unsigned)H) && ((unsigned)ww < (unsigned)W);
        float d = valid ? depth[(size_t)b * HW + (size_t)h * W + ww] : 0.f;
        float2 e = valid ? make_float2(__expf(-8.3f * d), __expf(8.3f * d))
                         : make_float2(0.f, 0.f);
        *(float2*)&xsl[r * ROWW + px * PXW + 16] = e;
    }

    __syncthreads();

    float2 dc[TBH];                              // center (em,ep) per output row
    #pragma unroll
    for (int o = 0; o < TBH; ++o)
        dc[o] = *(const float2*)&xsl[(o + 1) * ROWW + (pcl + 4) * PXW + 16];

    // ---- stage 2: per staged row r, load 3 B-chunks + 3 sims once, feed the
    // <=3 output rows that tap it (input row r serves output o = r - ki).
    #pragma unroll
    for (int r = 0; r < RR; ++r) {
        uint4 xraw[3]; float2 dn[3];
        #pragma unroll
        for (int kj = 0; kj < 3; ++kj) {
            int p = pcl + 3 + kj;                // global w = (w0+pcl) + kj - 1
            xraw[kj] = *(const uint4*)&xsl[r * ROWW + p * PXW + 4 * q];
            dn[kj]   = *(const float2*)&xsl[r * ROWW + p * PXW + 16];
        }
        #pragma unroll
        for (int kj = 0; kj < 3; ++kj) {
            #pragma unroll
            for (int ki = 0; ki < 3; ++ki) {
                int o = r - ki;
                if (o < 0 || o >= TBH) continue; // resolved at compile time
                int tap = ki * 3 + kj;
                float s = fminf(dn[kj].y * dc[o].x, dn[kj].x * dc[o].y); // exp(-8.3|dc-dn|)
                _Float16 hs = (_Float16)s;
                half8 sv = { hs, hs, hs, hs, hs, hs, hs, hs };
                half8 bf = __builtin_bit_cast(half8, xraw[kj]) * sv;    // 4x v_pk_mul_f16
                acc[o] = __builtin_amdgcn_mfma_f32_16x16x32_f16(af[tap], bf, acc[o], 0, 0, 0);
            }
        }
    }

    // ---- epilogue: wave writes 16 px x 16 ch x TBH rows
    const int pw = w0 + pcl;
    #pragma unroll
    for (int o = 0; o < TBH; ++o) {
        float* op = out + (size_t)b * C * HW + (size_t)(h0 + o) * W + pw;
        #pragma unroll
        for (int i = 0; i < 4; ++i)
            op[(size_t)(chh * 16 + q * 4 + i) * HW] = acc[o][i];
    }
}

extern "C" void kernel_launch(void* const* d_in, const int* in_sizes, int n_in,
                              void* d_out, int out_size, void* d_ws, size_t ws_size,
                              hipStream_t stream) {
    const float* x      = (const float*)d_in[0];
    const float* depth  = (const float*)d_in[1];
    const float* weight = (const float*)d_in[2];
    const float* bias   = (const float*)d_in[3];
    float* out          = (float*)d_out;

    uint4* wpk = (uint4*)d_ws;                   // 18.4 KB, only ws user

    hipLaunchKernelGGL(pack_w, dim3(5), dim3(256), 0, stream, weight, wpk);
    hipLaunchKernelGGL(depthconv_fused, dim3(2 * 128 * 16), dim3(256), 0, stream,
                       x, depth, wpk, bias, out);
}

// Round 3
// 142.502 us; speedup vs baseline: 1.2637x; 1.2637x over previous
//
#include <hip/hip_runtime.h>

typedef _Float16 half8 __attribute__((ext_vector_type(8)));
typedef float floatx4 __attribute__((ext_vector_type(4)));

constexpr int C = 32, H = 512, W = 512, HW = H * W;
constexpr int TBH = 8;             // output rows per block
constexpr int TBW = 32;            // output px per block
constexpr int RR  = TBH + 2;       // 10 staged input rows (h0-1 .. h0+8)
constexpr int PX  = TBW + 8;       // 40 staged px per row (w0-4 .. w0+35)
constexpr int PXW = 20;            // words/pixel: 16 x-fp16 + 2 depth(e-,e+) + 2 pad
                                   // (multiple of 4 keeps ds_*_b128 16B-aligned)
constexpr int ROWW = PX * PXW + 4; // 804 ; 804 % 32 == 4 skews rows across banks

__device__ __forceinline__ unsigned pack2h(float lo, float hi) {
    unsigned a = (unsigned)__builtin_bit_cast(unsigned short, (_Float16)lo);
    unsigned b = (unsigned)__builtin_bit_cast(unsigned short, (_Float16)hi);
    return a | (b << 16);
}

// ---- tiny kernel: weights -> per-lane fp16 A-fragment uint4s (18.4 KB, L2-hot)
__global__ __launch_bounds__(256) void pack_w(const float* __restrict__ weight,
                                              uint4* __restrict__ wp) {
    int j = blockIdx.x * 256 + threadIdx.x;
    if (j >= 1152) return;                       // 9 taps * 2 halves * 64 lanes
    int lane = j & 63, half = (j >> 6) & 1, tap = j >> 7;
    int o = half * 16 + (lane & 15), q = lane >> 4;
    uint4 v;
    v.x = pack2h(weight[(o * 32 + q * 8 + 0) * 9 + tap], weight[(o * 32 + q * 8 + 1) * 9 + tap]);
    v.y = pack2h(weight[(o * 32 + q * 8 + 2) * 9 + tap], weight[(o * 32 + q * 8 + 3) * 9 + tap]);
    v.z = pack2h(weight[(o * 32 + q * 8 + 4) * 9 + tap], weight[(o * 32 + q * 8 + 5) * 9 + tap]);
    v.w = pack2h(weight[(o * 32 + q * 8 + 6) * 9 + tap], weight[(o * 32 + q * 8 + 7) * 9 + tap]);
    wp[j] = v;
}

// ---- fused conv. LDS: [RR rows][PX px][20 words]; words 0..15 = 32ch fp16
// (word w = ch pair 2w,2w+1), words 16..17 = (exp(-8.3d), exp(+8.3d)).
// Reads: b128 at 20p+4q -> 8 bank-quads tiling 32 banks, 2 lanes each (free).
__global__ __launch_bounds__(256, 4) void depthconv_fused(
    const float* __restrict__ x, const float* __restrict__ depth,
    const uint4* __restrict__ wp, const float* __restrict__ bias,
    float* __restrict__ out)
{
    __shared__ __attribute__((aligned(16))) unsigned xsl[RR * ROWW];  // 32.2 KB

    const int bid  = blockIdx.x;                 // b(2) x hseg(64) x wseg(16)
    const int wseg = bid & 15, hseg = (bid >> 4) & 63, b = bid >> 10;
    const int h0 = hseg * TBH, w0 = wseg * TBW;
    const int tid = threadIdx.x;

    const int lane = tid & 63, wid = tid >> 6;
    const int nn = lane & 15, q = lane >> 4;
    const int chh = wid >> 1;                    // output-channel half
    const int pcl = (wid & 1) * 16 + nn;         // tile-local output px 0..31

    // A-frags + bias first: global latency overlaps stage-1 loads
    half8 af[9];
    #pragma unroll
    for (int tap = 0; tap < 9; ++tap)
        af[tap] = __builtin_bit_cast(half8, wp[(tap * 2 + chh) * 64 + lane]);

    floatx4 acc[TBH];                            // C/D: col=pixel nn, row(o)=4q+i
    #pragma unroll
    for (int i = 0; i < 4; ++i) {
        float bv = bias[chh * 16 + q * 4 + i];
        #pragma unroll
        for (int o = 0; o < TBH; ++o) acc[o][i] = bv;
    }

    // ---- stage 1a: x NCHW fp32 -> LDS fp16. unit = (cp, r, f4):
    // 2 coalesced float4 loads (ch 2cp, 2cp+1; 4 px) -> 4 b32 packed writes.
    // 16 cp * 10 r * 10 f4 = 1600 units; 7-trip unrolled so loads hoist.
    #pragma unroll
    for (int k = 0; k < 7; ++k) {
        int u = tid + k * 256;
        if (u < 16 * RR * (PX / 4)) {
            int f4 = u % 10, t = u / 10;
            int r = t % RR, cp = t / RR;
            int h = h0 - 1 + r, wst = w0 - 4 + f4 * 4;
            bool valid = ((unsigned)h < (unsigned)H) && ((unsigned)wst < (unsigned)W);
            float4 va = {0.f, 0.f, 0.f, 0.f}, vb = {0.f, 0.f, 0.f, 0.f};
            if (valid) {
                const float* xb = x + ((size_t)(b * C + 2 * cp)) * HW + (size_t)h * W + wst;
                va = *(const float4*)xb;
                vb = *(const float4*)(xb + HW);
            }
            unsigned* dst = &xsl[r * ROWW + (f4 * 4) * PXW + cp];
            dst[0 * PXW] = pack2h(va.x, vb.x);
            dst[1 * PXW] = pack2h(va.y, vb.y);
            dst[2 * PXW] = pack2h(va.z, vb.z);
            dst[3 * PXW] = pack2h(va.w, vb.w);
        }
    }

    // ---- stage 1b: depth -> (e^-8.3d, e^+8.3d) at words 16..17. 400 units.
    #pragma unroll
    for (int k = 0; k < 2; ++k) {
        int u = tid + k * 256;
        if (u < RR * PX) {
            int px = u % PX, r = u / PX;
            int h = h0 - 1 + r, ww = w0 - 4 + px;
            bool valid = ((unsigned)h < (unsigned)H) && ((unsigned)ww < (unsigned)W);
            float d = valid ? depth[(size_t)b * HW + (size_t)h * W + ww] : 0.f;
            float2 e = valid ? make_float2(__expf(-8.3f * d), __expf(8.3f * d))
                             : make_float2(0.f, 0.f);
            *(float2*)&xsl[r * ROWW + px * PXW + 16] = e;
        }
    }

    __syncthreads();

    float2 dc[TBH];                              // center (em,ep) per output row
    #pragma unroll
    for (int o = 0; o < TBH; ++o)
        dc[o] = *(const float2*)&xsl[(o + 1) * ROWW + (pcl + 4) * PXW + 16];

    // ---- stage 2: per staged row r, load 3 B-chunks + 3 sims once, feed the
    // <=3 output rows that tap it (input row r serves output o = r - ki).
    #pragma unroll
    for (int r = 0; r < RR; ++r) {
        uint4 xraw[3]; float2 dn[3];
        #pragma unroll
        for (int kj = 0; kj < 3; ++kj) {
            int p = pcl + 3 + kj;                // global w = (w0+pcl) + kj - 1
            xraw[kj] = *(const uint4*)&xsl[r * ROWW + p * PXW + 4 * q];
            dn[kj]   = *(const float2*)&xsl[r * ROWW + p * PXW + 16];
        }
        #pragma unroll
        for (int kj = 0; kj < 3; ++kj) {
            #pragma unroll
            for (int ki = 0; ki < 3; ++ki) {
                int o = r - ki;
                if (o < 0 || o >= TBH) continue; // resolved at compile time
                int tap = ki * 3 + kj;
                float s = fminf(dn[kj].y * dc[o].x, dn[kj].x * dc[o].y); // exp(-8.3|dc-dn|)
                _Float16 hs = (_Float16)s;
                half8 sv = { hs, hs, hs, hs, hs, hs, hs, hs };
                half8 bf = __builtin_bit_cast(half8, xraw[kj]) * sv;    // 4x v_pk_mul_f16
                acc[o] = __builtin_amdgcn_mfma_f32_16x16x32_f16(af[tap], bf, acc[o], 0, 0, 0);
            }
        }
    }

    // ---- epilogue: wave writes 16 px x 16 ch x 8 rows
    const int pw = w0 + pcl;
    #pragma unroll
    for (int o = 0; o < TBH; ++o) {
        float* op = out + (size_t)b * C * HW + (size_t)(h0 + o) * W + pw;
        #pragma unroll
        for (int i = 0; i < 4; ++i)
            op[(size_t)(chh * 16 + q * 4 + i) * HW] = acc[o][i];
    }
}

extern "C" void kernel_launch(void* const* d_in, const int* in_sizes, int n_in,
                              void* d_out, int out_size, void* d_ws, size_t ws_size,
                              hipStream_t stream) {
    const float* x      = (const float*)d_in[0];
    const float* depth  = (const float*)d_in[1];
    const float* weight = (const float*)d_in[2];
    const float* bias   = (const float*)d_in[3];
    float* out          = (float*)d_out;

    uint4* wpk = (uint4*)d_ws;                   // 18.4 KB, only ws user

    hipLaunchKernelGGL(pack_w, dim3(5), dim3(256), 0, stream, weight, wpk);
    hipLaunchKernelGGL(depthconv_fused, dim3(2 * 64 * 16), dim3(256), 0, stream,
                       x, depth, wpk, bias, out);
}